// Round 1
// baseline (574.888 us; speedup 1.0000x reference)
//
#include <hip/hip_runtime.h>
#include <hip/hip_bf16.h>

#define B_   64
#define N_   4096
#define NSTEPS 8

__device__ __forceinline__ float fast_sigmoid(float x) {
    return 1.0f / (1.0f + __expf(-x));
}
__device__ __forceinline__ float fast_tanh(float x) {
    // 1 - 2/(exp(2x)+1); correct limits at +/-inf, abs err ~1e-7
    return 1.0f - 2.0f / (1.0f + __expf(2.0f * x));
}

// ---------------------------------------------------------------------------
// Kernel 1: UGRNN recurrence. One thread per token (b,n).
// t = blockIdx*256+tid; b = t&63 (lane-minor => coalesced h_t stores),
// n = t>>6. Writes h transposed: h_t[(n*16+u)*64 + b]  (i-major, b-minor)
// Weights are uniform, constant-index => compiler emits s_load + SGPR-FMA.
// ---------------------------------------------------------------------------
__global__ __launch_bounds__(256) void ugrnn_recurrence(
    const float* __restrict__ inputs,
    const float* __restrict__ Wn, const float* __restrict__ Wg,
    const float* __restrict__ Ug, const float* __restrict__ bg,
    const float* __restrict__ Wc, const float* __restrict__ Uc,
    const float* __restrict__ bc, const float* __restrict__ We,
    const float* __restrict__ be, float* __restrict__ h_t)
{
    int t = blockIdx.x * 256 + threadIdx.x;
    int b = t & 63;
    int n = t >> 6;
    const float* ip = inputs + (size_t)(b * N_ + n) * 34;

    float h0 = ip[0];
    float e0 = ip[33];
    float nb[32];
#pragma unroll
    for (int k = 0; k < 32; ++k) nb[k] = ip[1 + k];

    float m[16];
#pragma unroll
    for (int u = 0; u < 16; ++u) m[u] = 0.0f;
#pragma unroll
    for (int k = 0; k < 32; ++k) {
        float xk = nb[k];
#pragma unroll
        for (int u = 0; u < 16; ++u) m[u] += xk * Wn[k * 16 + u];
    }

    float h[16], e[16];
#pragma unroll
    for (int u = 0; u < 16; ++u) { h[u] = h0; e[u] = e0; }

#pragma unroll 1   // keep I-footprint small; weights re-s_load from sKcache
    for (int step = 0; step < NSTEPS; ++step) {
        float x[16];
#pragma unroll
        for (int u = 0; u < 16; ++u) x[u] = m[u] + e[u];

        float ga[16], ca[16], ea[16];
#pragma unroll
        for (int u = 0; u < 16; ++u) { ga[u] = bg[u]; ca[u] = bc[u]; ea[u] = be[u]; }

#pragma unroll
        for (int k = 0; k < 16; ++k) {
            float xk = x[k], hk = h[k];
#pragma unroll
            for (int u = 0; u < 16; ++u) {
                ga[u] += xk * Wg[k * 16 + u];
                ga[u] += hk * Ug[k * 16 + u];
                ca[u] += xk * Wc[k * 16 + u];
                ca[u] += hk * Uc[k * 16 + u];
                ea[u] += xk * We[k * 16 + u];
            }
        }

#pragma unroll
        for (int u = 0; u < 16; ++u) {
            float g = fast_sigmoid(ga[u]);
            float c = fast_tanh(ca[u]);
            h[u] = g * h[u] + (1.0f - g) * c;
            e[u] = fast_tanh(ea[u]);
        }
    }

    float* hp = h_t + (size_t)(n * 16) * 64 + b;
#pragma unroll
    for (int u = 0; u < 16; ++u) hp[u * 64] = h[u];
}

// ---------------------------------------------------------------------------
// Kernel 2-init: out1[b][j] = b1[j]  (atomic targets must start at bias;
// ws is poisoned 0xAA before every launch)
// ---------------------------------------------------------------------------
__global__ __launch_bounds__(256) void init_out1(
    const float* __restrict__ b1, float* __restrict__ out1)
{
    int idx = blockIdx.x * 256 + threadIdx.x;   // grid 64 -> 16384
    out1[idx] = b1[idx & 255];
}

// ---------------------------------------------------------------------------
// Kernel 2a: split-K FC1.  out1[b][j] += sum_i h_t[i][b] * W1[i][j]
// grid 512 blocks x 256 threads; block owns 128 i-rows (2 sub-chunks of 64).
// thread = column j; 64 b-accumulators in VGPRs; h staged in LDS, read back
// as broadcast ds_read_b128 (same addr across lanes => conflict-free).
// W1 row loads are perfectly coalesced.
// ---------------------------------------------------------------------------
__global__ __launch_bounds__(256) void fc1_splitk(
    const float* __restrict__ h_t, const float* __restrict__ W1,
    float* __restrict__ out1)
{
    __shared__ float hs[64 * 64];   // 16 KB: hs[i][b]
    int j = threadIdx.x;
    int i0 = blockIdx.x * 128;

    float acc[64];
#pragma unroll
    for (int bb = 0; bb < 64; ++bb) acc[bb] = 0.0f;

    for (int s = 0; s < 2; ++s) {
        int ibase = i0 + s * 64;
        __syncthreads();
        const float4* src = (const float4*)(h_t + (size_t)ibase * 64);
        float4* dst = (float4*)hs;
#pragma unroll
        for (int r = 0; r < 4; ++r) dst[j + r * 256] = src[j + r * 256];
        __syncthreads();

        for (int i = 0; i < 64; ++i) {
            float w = W1[(size_t)(ibase + i) * 256 + j];
            const float4* hp = (const float4*)&hs[i * 64];
#pragma unroll
            for (int b4 = 0; b4 < 16; ++b4) {
                float4 h4 = hp[b4];
                acc[b4 * 4 + 0] += h4.x * w;
                acc[b4 * 4 + 1] += h4.y * w;
                acc[b4 * 4 + 2] += h4.z * w;
                acc[b4 * 4 + 3] += h4.w * w;
            }
        }
    }

#pragma unroll 1
    for (int bb = 0; bb < 64; ++bb)
        atomicAdd(&out1[bb * 256 + j], acc[bb]);
}

// ---------------------------------------------------------------------------
// Kernel 2c: tail MLP + softmax. One block per batch row b.
// out2 = relu(relu(out1) @ W2 + b2); probs = softmax(out2 @ W3 + b3)
// ---------------------------------------------------------------------------
__global__ __launch_bounds__(64) void mlp_tail(
    const float* __restrict__ out1, const float* __restrict__ W2,
    const float* __restrict__ b2, const float* __restrict__ W3,
    const float* __restrict__ b3, float* __restrict__ out)
{
    __shared__ float x1[256];
    __shared__ float x2[32];
    __shared__ float lg[2];
    int b = blockIdx.x, tid = threadIdx.x;

#pragma unroll
    for (int r = 0; r < 4; ++r) {
        float v = out1[b * 256 + tid * 4 + r];
        x1[tid * 4 + r] = fmaxf(v, 0.0f);
    }
    __syncthreads();

    if (tid < 32) {
        float s = b2[tid];
        for (int k = 0; k < 256; ++k) s += x1[k] * W2[k * 32 + tid];
        x2[tid] = fmaxf(s, 0.0f);
    }
    __syncthreads();

    if (tid < 2) {
        float s = b3[tid];
#pragma unroll
        for (int k = 0; k < 32; ++k) s += x2[k] * W3[k * 2 + tid];
        lg[tid] = s;
    }
    __syncthreads();

    if (tid == 0) {
        float mx = fmaxf(lg[0], lg[1]);
        float e0 = __expf(lg[0] - mx), e1 = __expf(lg[1] - mx);
        float inv = 1.0f / (e0 + e1);
        out[b * 2 + 0] = e0 * inv;
        out[b * 2 + 1] = e1 * inv;
    }
}

// ---------------------------------------------------------------------------
extern "C" void kernel_launch(void* const* d_in, const int* in_sizes, int n_in,
                              void* d_out, int out_size, void* d_ws, size_t ws_size,
                              hipStream_t stream) {
    const float* inputs = (const float*)d_in[0];
    const float* Wn = (const float*)d_in[1];
    const float* Wg = (const float*)d_in[2];
    const float* Ug = (const float*)d_in[3];
    const float* bg = (const float*)d_in[4];
    const float* Wc = (const float*)d_in[5];
    const float* Uc = (const float*)d_in[6];
    const float* bc = (const float*)d_in[7];
    const float* We = (const float*)d_in[8];
    const float* be = (const float*)d_in[9];
    const float* W1 = (const float*)d_in[10];
    const float* b1 = (const float*)d_in[11];
    const float* W2 = (const float*)d_in[12];
    const float* b2 = (const float*)d_in[13];
    const float* W3 = (const float*)d_in[14];
    const float* b3 = (const float*)d_in[15];
    float* out = (float*)d_out;

    // workspace layout
    float* h_t  = (float*)d_ws;                                  // 65536*64 f32 = 16 MB
    float* out1 = (float*)((char*)d_ws + (size_t)65536 * 64 * 4); // 64*256 f32 = 64 KB

    ugrnn_recurrence<<<1024, 256, 0, stream>>>(inputs, Wn, Wg, Ug, bg, Wc, Uc, bc,
                                               We, be, h_t);
    init_out1<<<64, 256, 0, stream>>>(b1, out1);
    fc1_splitk<<<512, 256, 0, stream>>>(h_t, W1, out1);
    mlp_tail<<<64, 64, 0, stream>>>(out1, W2, b2, W3, b3, out);
}

// Round 2
// 505.655 us; speedup vs baseline: 1.1369x; 1.1369x over previous
//
#include <hip/hip_runtime.h>
#include <hip/hip_bf16.h>

#define B_   64
#define N_   4096
#define NSTEPS 8

__device__ __forceinline__ float fast_sigmoid(float x) {
    return 1.0f / (1.0f + __expf(-x));
}
__device__ __forceinline__ float fast_tanh(float x) {
    // 1 - 2/(exp(2x)+1); correct limits at +/-inf
    return 1.0f - 2.0f / (1.0f + __expf(2.0f * x));
}

// ---------------------------------------------------------------------------
// Kernel 1: UGRNN recurrence. One thread per token (b,n).
// Sequential accumulator passes keep peak live floats ~80 so nothing spills
// under the 128-VGPR cap from __launch_bounds__(256,4) (4 waves/SIMD => the
// whole 4096-wave grid is co-resident).
// Writes h transposed: h_t[(n*16+u)*64 + b]  (i-major, b-minor, coalesced).
// ---------------------------------------------------------------------------
__global__ __launch_bounds__(256, 4) void ugrnn_recurrence(
    const float* __restrict__ inputs,
    const float* __restrict__ Wn, const float* __restrict__ Wg,
    const float* __restrict__ Ug, const float* __restrict__ bg,
    const float* __restrict__ Wc, const float* __restrict__ Uc,
    const float* __restrict__ bc, const float* __restrict__ We,
    const float* __restrict__ be, float* __restrict__ h_t)
{
    int t = blockIdx.x * 256 + threadIdx.x;
    int b = t & 63;
    int n = t >> 6;
    const float* ip = inputs + (size_t)(b * N_ + n) * 34;

    float h0 = ip[0];
    float e0 = ip[33];

    // m = neigh @ Wn   (32x16)
    float m[16];
#pragma unroll
    for (int u = 0; u < 16; ++u) m[u] = 0.0f;
#pragma unroll
    for (int k = 0; k < 32; ++k) {
        float xk = ip[1 + k];
#pragma unroll
        for (int u = 0; u < 16; ++u) m[u] += xk * Wn[k * 16 + u];
    }

    float h[16], e[16];
#pragma unroll
    for (int u = 0; u < 16; ++u) { h[u] = h0; e[u] = e0; }

#pragma unroll 1   // keep I-footprint and SGPR pressure small
    for (int step = 0; step < NSTEPS; ++step) {
        float x[16];
#pragma unroll
        for (int u = 0; u < 16; ++u) x[u] = m[u] + e[u];
        // e is dead now until rewritten in pass 3

        // ---- pass 1: g = sigmoid(x@Wg + h@Ug + bg) ----
        float g[16];
#pragma unroll
        for (int u = 0; u < 16; ++u) g[u] = bg[u];
#pragma unroll
        for (int k = 0; k < 16; ++k) {
            float xk = x[k], hk = h[k];
#pragma unroll
            for (int u = 0; u < 16; ++u) {
                g[u] += xk * Wg[k * 16 + u];
                g[u] += hk * Ug[k * 16 + u];
            }
        }
#pragma unroll
        for (int u = 0; u < 16; ++u) g[u] = fast_sigmoid(g[u]);

        // ---- pass 2: c = tanh(x@Wc + h@Uc + bc); h = g*h + (1-g)*c ----
        float c[16];
#pragma unroll
        for (int u = 0; u < 16; ++u) c[u] = bc[u];
#pragma unroll
        for (int k = 0; k < 16; ++k) {
            float xk = x[k], hk = h[k];
#pragma unroll
            for (int u = 0; u < 16; ++u) {
                c[u] += xk * Wc[k * 16 + u];
                c[u] += hk * Uc[k * 16 + u];
            }
        }
#pragma unroll
        for (int u = 0; u < 16; ++u) {
            float gv = g[u];
            h[u] = gv * h[u] + (1.0f - gv) * fast_tanh(c[u]);
        }

        // ---- pass 3: e = tanh(x@We + be) ----
#pragma unroll
        for (int u = 0; u < 16; ++u) e[u] = be[u];
#pragma unroll
        for (int k = 0; k < 16; ++k) {
            float xk = x[k];
#pragma unroll
            for (int u = 0; u < 16; ++u) e[u] += xk * We[k * 16 + u];
        }
#pragma unroll
        for (int u = 0; u < 16; ++u) e[u] = fast_tanh(e[u]);
    }

    float* hp = h_t + (size_t)(n * 16) * 64 + b;
#pragma unroll
    for (int u = 0; u < 16; ++u) hp[u * 64] = h[u];
}

// ---------------------------------------------------------------------------
// Kernel 2-init: out1[b][j] = b1[j]  (atomic targets start at bias)
// ---------------------------------------------------------------------------
__global__ __launch_bounds__(256) void init_out1(
    const float* __restrict__ b1, float* __restrict__ out1)
{
    int idx = blockIdx.x * 256 + threadIdx.x;   // grid 64 -> 16384
    out1[idx] = b1[idx & 255];
}

// ---------------------------------------------------------------------------
// Kernel 2a: split-K FC1.  out1[b][j] += sum_i h_t[i][b] * W1[i][j]
// No LDS: h_t[i*64+b] has a wave-uniform address -> compiler scalarizes to
// s_load through the constant cache; the FMA consumes it as the SGPR operand.
// W1[i*256+j] is the per-lane coalesced vector load. 64 b-accumulators in
// VGPRs (fits under the 128 cap from __launch_bounds__(256,4)).
// ---------------------------------------------------------------------------
__global__ __launch_bounds__(256, 4) void fc1_splitk(
    const float* __restrict__ h_t, const float* __restrict__ W1,
    float* __restrict__ out1)
{
    int j = threadIdx.x;
    int i0 = blockIdx.x * 128;

    float acc[64];
#pragma unroll
    for (int bb = 0; bb < 64; ++bb) acc[bb] = 0.0f;

#pragma unroll 1
    for (int i = 0; i < 128; ++i) {
        float w = W1[(size_t)(i0 + i) * 256 + j];      // coalesced
        const float* hrow = h_t + (size_t)(i0 + i) * 64; // uniform address
#pragma unroll
        for (int bb = 0; bb < 64; ++bb)
            acc[bb] += hrow[bb] * w;                    // s_load + SGPR-FMA
    }

#pragma unroll 1
    for (int bb = 0; bb < 64; ++bb)
        atomicAdd(&out1[bb * 256 + j], acc[bb]);
}

// ---------------------------------------------------------------------------
// Kernel 2c: tail MLP + softmax. One block per batch row b.
// ---------------------------------------------------------------------------
__global__ __launch_bounds__(64) void mlp_tail(
    const float* __restrict__ out1, const float* __restrict__ W2,
    const float* __restrict__ b2, const float* __restrict__ W3,
    const float* __restrict__ b3, float* __restrict__ out)
{
    __shared__ float x1[256];
    __shared__ float x2[32];
    __shared__ float lg[2];
    int b = blockIdx.x, tid = threadIdx.x;

#pragma unroll
    for (int r = 0; r < 4; ++r) {
        float v = out1[b * 256 + tid * 4 + r];
        x1[tid * 4 + r] = fmaxf(v, 0.0f);
    }
    __syncthreads();

    if (tid < 32) {
        float s = b2[tid];
        for (int k = 0; k < 256; ++k) s += x1[k] * W2[k * 32 + tid];
        x2[tid] = fmaxf(s, 0.0f);
    }
    __syncthreads();

    if (tid < 2) {
        float s = b3[tid];
#pragma unroll
        for (int k = 0; k < 32; ++k) s += x2[k] * W3[k * 2 + tid];
        lg[tid] = s;
    }
    __syncthreads();

    if (tid == 0) {
        float mx = fmaxf(lg[0], lg[1]);
        float e0 = __expf(lg[0] - mx), e1 = __expf(lg[1] - mx);
        float inv = 1.0f / (e0 + e1);
        out[b * 2 + 0] = e0 * inv;
        out[b * 2 + 1] = e1 * inv;
    }
}

// ---------------------------------------------------------------------------
extern "C" void kernel_launch(void* const* d_in, const int* in_sizes, int n_in,
                              void* d_out, int out_size, void* d_ws, size_t ws_size,
                              hipStream_t stream) {
    const float* inputs = (const float*)d_in[0];
    const float* Wn = (const float*)d_in[1];
    const float* Wg = (const float*)d_in[2];
    const float* Ug = (const float*)d_in[3];
    const float* bg = (const float*)d_in[4];
    const float* Wc = (const float*)d_in[5];
    const float* Uc = (const float*)d_in[6];
    const float* bc = (const float*)d_in[7];
    const float* We = (const float*)d_in[8];
    const float* be = (const float*)d_in[9];
    const float* W1 = (const float*)d_in[10];
    const float* b1 = (const float*)d_in[11];
    const float* W2 = (const float*)d_in[12];
    const float* b2 = (const float*)d_in[13];
    const float* W3 = (const float*)d_in[14];
    const float* b3 = (const float*)d_in[15];
    float* out = (float*)d_out;

    // workspace layout
    float* h_t  = (float*)d_ws;                                   // 65536*64 f32 = 16 MB
    float* out1 = (float*)((char*)d_ws + (size_t)65536 * 64 * 4); // 64*256 f32 = 64 KB

    ugrnn_recurrence<<<1024, 256, 0, stream>>>(inputs, Wn, Wg, Ug, bg, Wc, Uc, bc,
                                               We, be, h_t);
    init_out1<<<64, 256, 0, stream>>>(b1, out1);
    fc1_splitk<<<512, 256, 0, stream>>>(h_t, W1, out1);
    mlp_tail<<<64, 64, 0, stream>>>(out1, W2, b2, W3, b3, out);
}